// Round 2
// baseline (85.423 us; speedup 1.0000x reference)
//
#include <hip/hip_runtime.h>
#include <hip/hip_cooperative_groups.h>
#include <math.h>

namespace cg = cooperative_groups;

#define N_NODES 2048
#define N_RELS  16
#define N_FEAT  256
#define BLOCKS  512
#define THREADS 256

__device__ __forceinline__ float sigmoidf_fast(float z) {
    return 1.0f / (1.0f + __expf(-z));
}

// Fused: phase 1 computes A[r][n] = dot(x[n], relations[r]) and
// B[n] = dot(x[n], outer_weight) (one wave per node); grid sync; phase 2
// gathers per-edge sigmoid(A[rel][src] * B[dst]) (2 edges per thread).
__global__ void __launch_bounds__(THREADS, 2)
fused_kernel(const float* __restrict__ x,
             const float* __restrict__ relations,
             const float* __restrict__ outer_weight,
             const int* __restrict__ edge_index,
             float* __restrict__ out,
             float* __restrict__ A,   // [N_RELS][N_NODES] in d_ws
             float* __restrict__ B,   // [N_NODES] in d_ws
             int E)
{
    const int t    = blockIdx.x * blockDim.x + threadIdx.x;
    const int lane = threadIdx.x & 63;
    const int n    = t >> 6;  // one 64-lane wave per node

    // ---- Phase 1: rank-1 factor precompute ----
    if (n < N_NODES) {
        const float4 xv = reinterpret_cast<const float4*>(x + n * N_FEAT)[lane];
        const float4 wv = reinterpret_cast<const float4*>(outer_weight)[lane];

        float b = xv.x * wv.x + xv.y * wv.y + xv.z * wv.z + xv.w * wv.w;
        #pragma unroll
        for (int off = 32; off > 0; off >>= 1) b += __shfl_xor(b, off, 64);
        if (lane == 0) B[n] = b;

        #pragma unroll
        for (int r = 0; r < N_RELS; ++r) {
            const float4 rv =
                reinterpret_cast<const float4*>(relations + r * N_FEAT)[lane];
            float a = xv.x * rv.x + xv.y * rv.y + xv.z * rv.z + xv.w * rv.w;
            #pragma unroll
            for (int off = 32; off > 0; off >>= 1) a += __shfl_xor(a, off, 64);
            if (lane == 0) A[r * N_NODES + n] = a;
        }
    }

    __threadfence();          // make A/B visible device-wide (cross-XCD)
    cg::this_grid().sync();

    // ---- Phase 2: per-edge gather + sigmoid ----
    const int* __restrict__ src = edge_index;
    const int* __restrict__ rel = edge_index + E;
    const int* __restrict__ dst = edge_index + 2 * E;

    const int e2 = t * 2;
    if (e2 + 1 < E) {
        const int2 s = *reinterpret_cast<const int2*>(src + e2);
        const int2 r = *reinterpret_cast<const int2*>(rel + e2);
        const int2 d = *reinterpret_cast<const int2*>(dst + e2);
        float2 o;
        o.x = sigmoidf_fast(A[r.x * N_NODES + s.x] * B[d.x]);
        o.y = sigmoidf_fast(A[r.y * N_NODES + s.y] * B[d.y]);
        *reinterpret_cast<float2*>(out + e2) = o;
    } else if (e2 < E) {
        for (int e = e2; e < E; ++e)
            out[e] = sigmoidf_fast(A[rel[e] * N_NODES + src[e]] * B[dst[e]]);
    }
    // Tail beyond grid capacity (robustness; exact fit for E=262144)
    for (int e = BLOCKS * THREADS * 2 + t; e < E; e += BLOCKS * THREADS)
        out[e] = sigmoidf_fast(A[rel[e] * N_NODES + src[e]] * B[dst[e]]);
}

extern "C" void kernel_launch(void* const* d_in, const int* in_sizes, int n_in,
                              void* d_out, int out_size, void* d_ws, size_t ws_size,
                              hipStream_t stream) {
    const float* x            = (const float*)d_in[0];
    const float* relations    = (const float*)d_in[1];
    const float* outer_weight = (const float*)d_in[2];
    const int*   edge_index   = (const int*)d_in[3];

    int E = in_sizes[3] / 3;  // edge_index is [3, E]: rows src, rel, dst

    float* A = (float*)d_ws;             // 16*2048 floats = 128 KB
    float* B = A + N_RELS * N_NODES;     // 2048 floats
    float* out = (float*)d_out;

    void* args[] = {(void*)&x, (void*)&relations, (void*)&outer_weight,
                    (void*)&edge_index, (void*)&out, (void*)&A, (void*)&B,
                    (void*)&E};
    hipLaunchCooperativeKernel((void*)fused_kernel, dim3(BLOCKS), dim3(THREADS),
                               args, 0, stream);
}

// Round 3
// 60.777 us; speedup vs baseline: 1.4055x; 1.4055x over previous
//
#include <hip/hip_runtime.h>
#include <math.h>

#define N_NODES 2048
#define N_RELS  16
#define N_FEAT  256
#define BLOCKS  512
#define THREADS 256

__device__ __forceinline__ float sigmoidf_fast(float z) {
    return 1.0f / (1.0f + __expf(-z));
}

// Single cooperative kernel, hand-rolled lightweight barrier.
// Phase 1: one 64-lane wave per node computes A[r][n]=dot(x[n],rel[r]),
//          B[n]=dot(x[n],w); written with agent-scope stores (write-through
//          to the die-level coherence point -> no L2 flush needed).
// Barrier: vmcnt drain + relaxed agent-scope counter (no cache maintenance).
// Phase 2: per-edge gather via agent-scope loads (bypass stale L1/L2).
__global__ void __launch_bounds__(THREADS, 2)
fused_kernel(const float* __restrict__ x,
             const float* __restrict__ relations,
             const float* __restrict__ outer_weight,
             const int* __restrict__ edge_index,
             float* __restrict__ out,
             float* A,            // [N_RELS][N_NODES] in d_ws
             float* B,            // [N_NODES] in d_ws
             unsigned int* ctr,   // barrier counter in d_ws (memset to 0/call)
             int E)
{
    const int t    = blockIdx.x * blockDim.x + threadIdx.x;
    const int lane = threadIdx.x & 63;
    const int n    = t >> 6;  // one wave per node; 2048 waves == N_NODES

    // ---- Phase 1 ----
    if (n < N_NODES) {
        const float4 xv = reinterpret_cast<const float4*>(x + n * N_FEAT)[lane];
        const float4 wv = reinterpret_cast<const float4*>(outer_weight)[lane];

        float b = xv.x * wv.x + xv.y * wv.y + xv.z * wv.z + xv.w * wv.w;
        #pragma unroll
        for (int off = 32; off > 0; off >>= 1) b += __shfl_xor(b, off, 64);
        if (lane == 0)
            __hip_atomic_store(&B[n], b, __ATOMIC_RELAXED,
                               __HIP_MEMORY_SCOPE_AGENT);

        #pragma unroll
        for (int r = 0; r < N_RELS; ++r) {
            const float4 rv =
                reinterpret_cast<const float4*>(relations + r * N_FEAT)[lane];
            float a = xv.x * rv.x + xv.y * rv.y + xv.z * rv.z + xv.w * rv.w;
            #pragma unroll
            for (int off = 32; off > 0; off >>= 1) a += __shfl_xor(a, off, 64);
            if (lane == 0)
                __hip_atomic_store(&A[r * N_NODES + n], a, __ATOMIC_RELAXED,
                                   __HIP_MEMORY_SCOPE_AGENT);
        }
    }

    // ---- Lightweight device-wide barrier (no L2 flush) ----
    asm volatile("s_waitcnt vmcnt(0)" ::: "memory");  // my stores reached MALL
    __syncthreads();                                   // whole block's stores done
    if (threadIdx.x == 0) {
        __hip_atomic_fetch_add(ctr, 1u, __ATOMIC_RELAXED,
                               __HIP_MEMORY_SCOPE_AGENT);
        while (__hip_atomic_load(ctr, __ATOMIC_RELAXED,
                                 __HIP_MEMORY_SCOPE_AGENT) < BLOCKS) {}
    }
    __syncthreads();  // compiler + exec fence: no gather hoisted above spin

    // ---- Phase 2: 2 edges per thread ----
    const int* __restrict__ src = edge_index;
    const int* __restrict__ rel = edge_index + E;
    const int* __restrict__ dst = edge_index + 2 * E;

    const int e2 = t * 2;
    if (e2 + 1 < E) {
        const int2 s = *reinterpret_cast<const int2*>(src + e2);
        const int2 r = *reinterpret_cast<const int2*>(rel + e2);
        const int2 d = *reinterpret_cast<const int2*>(dst + e2);
        const float a0 = __hip_atomic_load(&A[r.x * N_NODES + s.x],
                                           __ATOMIC_RELAXED, __HIP_MEMORY_SCOPE_AGENT);
        const float b0 = __hip_atomic_load(&B[d.x],
                                           __ATOMIC_RELAXED, __HIP_MEMORY_SCOPE_AGENT);
        const float a1 = __hip_atomic_load(&A[r.y * N_NODES + s.y],
                                           __ATOMIC_RELAXED, __HIP_MEMORY_SCOPE_AGENT);
        const float b1 = __hip_atomic_load(&B[d.y],
                                           __ATOMIC_RELAXED, __HIP_MEMORY_SCOPE_AGENT);
        float2 o;
        o.x = sigmoidf_fast(a0 * b0);
        o.y = sigmoidf_fast(a1 * b1);
        *reinterpret_cast<float2*>(out + e2) = o;
    } else if (e2 < E) {
        for (int e = e2; e < E; ++e) {
            const float a0 = __hip_atomic_load(&A[rel[e] * N_NODES + src[e]],
                                               __ATOMIC_RELAXED, __HIP_MEMORY_SCOPE_AGENT);
            const float b0 = __hip_atomic_load(&B[dst[e]],
                                               __ATOMIC_RELAXED, __HIP_MEMORY_SCOPE_AGENT);
            out[e] = sigmoidf_fast(a0 * b0);
        }
    }
    // Tail beyond grid capacity (no-op for E = 262144, kept for robustness)
    for (int e = BLOCKS * THREADS * 2 + t; e < E; e += BLOCKS * THREADS) {
        const float a0 = __hip_atomic_load(&A[rel[e] * N_NODES + src[e]],
                                           __ATOMIC_RELAXED, __HIP_MEMORY_SCOPE_AGENT);
        const float b0 = __hip_atomic_load(&B[dst[e]],
                                           __ATOMIC_RELAXED, __HIP_MEMORY_SCOPE_AGENT);
        out[e] = sigmoidf_fast(a0 * b0);
    }
}

extern "C" void kernel_launch(void* const* d_in, const int* in_sizes, int n_in,
                              void* d_out, int out_size, void* d_ws, size_t ws_size,
                              hipStream_t stream) {
    const float* x            = (const float*)d_in[0];
    const float* relations    = (const float*)d_in[1];
    const float* outer_weight = (const float*)d_in[2];
    const int*   edge_index   = (const int*)d_in[3];

    int E = in_sizes[3] / 3;  // edge_index is [3, E]: rows src, rel, dst

    float* A = (float*)d_ws;                   // 16*2048 floats = 128 KB
    float* B = A + N_RELS * N_NODES;           // 2048 floats = 8 KB
    unsigned int* ctr =
        (unsigned int*)((char*)d_ws + 144 * 1024);  // aligned, past A+B
    float* out = (float*)d_out;

    hipMemsetAsync(ctr, 0, sizeof(unsigned int), stream);

    void* args[] = {(void*)&x, (void*)&relations, (void*)&outer_weight,
                    (void*)&edge_index, (void*)&out, (void*)&A, (void*)&B,
                    (void*)&ctr, (void*)&E};
    hipLaunchCooperativeKernel((void*)fused_kernel, dim3(BLOCKS), dim3(THREADS),
                               args, 0, stream);
}

// Round 5
// 12.861 us; speedup vs baseline: 6.6422x; 4.7259x over previous
//
#include <hip/hip_runtime.h>
#include <math.h>

#define N_NODES 2048
#define N_RELS  16
#define N_FEAT  256
#define N_JOBS  (N_RELS + 1)          // 16 relation dots + 1 outer_weight dot
#define THREADS 256

typedef int   v2i __attribute__((ext_vector_type(2)));
typedef float v2f __attribute__((ext_vector_type(2)));

__device__ __forceinline__ float sigmoidf_fast(float z) {
    return 1.0f / (1.0f + __expf(-z));
}

// Kernel 1: one 64-lane wave per (node, j) job, j in [0,17):
//   j < 16 : A[j][n] = dot(x[n], relations[j])
//   j == 16: B[n]    = dot(x[n], outer_weight)
// Each wave: two coalesced 1KB row loads (float4/lane), 4 FMAs, one 6-step
// shuffle reduce. No serial per-wave chains; 34816 waves stream ~32/SIMD.
__global__ void __launch_bounds__(THREADS)
precompute_kernel(const float* __restrict__ x,
                  const float* __restrict__ relations,
                  const float* __restrict__ outer_weight,
                  float* __restrict__ A,   // [N_RELS][N_NODES]
                  float* __restrict__ B)   // [N_NODES]
{
    const int t    = blockIdx.x * blockDim.x + threadIdx.x;
    const int w    = t >> 6;
    const int lane = t & 63;
    if (w >= N_NODES * N_JOBS) return;

    const int n = w / N_JOBS;
    const int j = w - n * N_JOBS;

    const float4 xv = reinterpret_cast<const float4*>(x + n * N_FEAT)[lane];
    const float* rbase = (j < N_RELS) ? (relations + j * N_FEAT) : outer_weight;
    const float4 rv = reinterpret_cast<const float4*>(rbase)[lane];

    float a = xv.x * rv.x + xv.y * rv.y + xv.z * rv.z + xv.w * rv.w;
    #pragma unroll
    for (int off = 32; off > 0; off >>= 1) a += __shfl_xor(a, off, 64);

    if (lane == 0) {
        if (j < N_RELS) A[j * N_NODES + n] = a;
        else            B[n] = a;
    }
}

// Kernel 2: out[e] = sigmoid(A[rel[e]][src[e]] * B[dst[e]]), 2 edges/thread.
// Streamed data (indices, out) uses nontemporal accesses to keep A/B in L2.
__global__ void __launch_bounds__(THREADS)
edge_kernel(const int* __restrict__ src,
            const int* __restrict__ rel,
            const int* __restrict__ dst,
            const float* __restrict__ A,
            const float* __restrict__ B,
            float* __restrict__ out,
            int E)
{
    const int t  = blockIdx.x * blockDim.x + threadIdx.x;
    const int e2 = t * 2;
    if (e2 + 1 < E) {
        const v2i s = __builtin_nontemporal_load(
            reinterpret_cast<const v2i*>(src + e2));
        const v2i r = __builtin_nontemporal_load(
            reinterpret_cast<const v2i*>(rel + e2));
        const v2i d = __builtin_nontemporal_load(
            reinterpret_cast<const v2i*>(dst + e2));
        // 4 independent gathers, all in flight together
        const float a0 = A[r.x * N_NODES + s.x];
        const float a1 = A[r.y * N_NODES + s.y];
        const float b0 = B[d.x];
        const float b1 = B[d.y];
        v2f o;
        o.x = sigmoidf_fast(a0 * b0);
        o.y = sigmoidf_fast(a1 * b1);
        __builtin_nontemporal_store(o, reinterpret_cast<v2f*>(out + e2));
    } else if (e2 < E) {
        for (int e = e2; e < E; ++e)
            out[e] = sigmoidf_fast(A[rel[e] * N_NODES + src[e]] * B[dst[e]]);
    }
}

extern "C" void kernel_launch(void* const* d_in, const int* in_sizes, int n_in,
                              void* d_out, int out_size, void* d_ws, size_t ws_size,
                              hipStream_t stream) {
    const float* x            = (const float*)d_in[0];
    const float* relations    = (const float*)d_in[1];
    const float* outer_weight = (const float*)d_in[2];
    const int*   edge_index   = (const int*)d_in[3];

    const int E = in_sizes[3] / 3;  // edge_index is [3, E]: rows src, rel, dst
    const int* src = edge_index;
    const int* rel = edge_index + E;
    const int* dst = edge_index + 2 * E;

    float* A = (float*)d_ws;             // 16*2048 floats = 128 KB
    float* B = A + N_RELS * N_NODES;     // 2048 floats = 8 KB

    const int total_pre_threads = N_NODES * N_JOBS * 64;   // 34816 waves
    const int pre_blocks = (total_pre_threads + THREADS - 1) / THREADS;
    precompute_kernel<<<pre_blocks, THREADS, 0, stream>>>(
        x, relations, outer_weight, A, B);

    const int work = (E + 1) / 2;
    const int edge_blocks = (work + THREADS - 1) / THREADS;
    edge_kernel<<<edge_blocks, THREADS, 0, stream>>>(
        src, rel, dst, A, B, (float*)d_out, E);
}